// Round 7
// baseline (474.353 us; speedup 1.0000x reference)
//
#include <hip/hip_runtime.h>
#include <stdint.h>

#define N_COLS   32768
#define N_ROWS   256
#define N_TASKS  512          // 256 rows x {predictions, targets}
#define B1       2048         // level-1 bins (top 11 bits of key)
#define SHIFT1   21
#define SHIFT2   13           // level-2 bins: bits [20:13]
#define MASK2    255u
#define B2       256
#define SMALL_THR 64u
#define CAP_W    2048         // per-wave LDS bucket capacity (expected max ~1400)
#define HREP     4            // per-wave histogram/cursor replicas (contention split)
#define HTOT     (B1 * HREP)  // 8192 u32 per task

// order-preserving float->uint32 key
__device__ __forceinline__ uint32_t fkey(float x) {
    uint32_t u = __float_as_uint(x);
    return u ^ ((uint32_t)((int32_t)u >> 31) | 0x80000000u);
}

__device__ __forceinline__ const float* task_src(int t, const float* P, const float* Tg) {
    return (t < N_ROWS ? P : Tg) + (size_t)(t & (N_ROWS - 1)) * N_COLS;
}

// ---- K1: per-task histogram, 4 replicas per bin (measured-good) ----
// element->replica mapping (512 threads, j4 stride 512, rep=(tid>>6)&3) MUST match k_scatter.
__global__ void __launch_bounds__(512) k_hist(const float* P, const float* Tg, uint32_t* hist) {
    int t = blockIdx.x;
    const float* src = task_src(t, P, Tg);
    __shared__ uint32_t h[HTOT];
    for (int i = threadIdx.x; i < HTOT; i += 512) h[i] = 0;
    __syncthreads();
    int rep = (threadIdx.x >> 6) & 3;
    for (int j4 = threadIdx.x; j4 < N_COLS / 4; j4 += 512) {
        float4 v = ((const float4*)src)[j4];
        atomicAdd(&h[((fkey(v.x) >> SHIFT1) << 2) + rep], 1u);
        atomicAdd(&h[((fkey(v.y) >> SHIFT1) << 2) + rep], 1u);
        atomicAdd(&h[((fkey(v.z) >> SHIFT1) << 2) + rep], 1u);
        atomicAdd(&h[((fkey(v.w) >> SHIFT1) << 2) + rep], 1u);
    }
    __syncthreads();
    uint32_t* o = hist + (size_t)t * HTOT;
    for (int i = threadIdx.x; i < HTOT; i += 512) o[i] = h[i];
}

// ---- K2: per-task exclusive prefix -> per-replica cursors + work lists ----
__global__ void __launch_bounds__(256) k_scan(uint32_t* hist, uint32_t* cnts,
                                              unsigned long long* list, unsigned long long* slist) {
    int t = blockIdx.x;
    uint4* h4 = (uint4*)(hist + (size_t)t * HTOT);
    __shared__ uint32_t stmp[256];
    uint32_t run = 0;
    for (int c = 0; c < B1 / 256; ++c) {
        int bin = c * 256 + threadIdx.x;
        uint4 hv = h4[bin];
        uint32_t v = hv.x + hv.y + hv.z + hv.w;
        stmp[threadIdx.x] = v;
        __syncthreads();
        for (int off = 1; off < 256; off <<= 1) {
            uint32_t x = (threadIdx.x >= (unsigned)off) ? stmp[threadIdx.x - off] : 0u;
            __syncthreads();
            stmp[threadIdx.x] += x;
            __syncthreads();
        }
        uint32_t incl = stmp[threadIdx.x];
        uint32_t tot  = stmp[255];
        uint32_t start = run + incl - v;     // task-local exclusive prefix (bucket start)
        if (v > SMALL_THR) {
            uint32_t p = atomicAdd(&cnts[0], 1u);
            list[p] = ((unsigned long long)t << 32) | ((unsigned long long)start << 16) | v;
        } else if (v) {
            uint32_t p = atomicAdd(&cnts[1], 1u);
            slist[p] = ((unsigned long long)t << 32) | ((unsigned long long)start << 16) | v;
        }
        uint4 w;                              // per-replica cursor starts
        w.x = start;
        w.y = w.x + hv.x;
        w.z = w.y + hv.y;
        w.w = w.z + hv.z;
        h4[bin] = w;
        run += tot;
        __syncthreads();
    }
}

// ---- K3: counting-sort scatter, LDS cursors, ONE packed 8B store per element ----
__global__ void __launch_bounds__(512) k_scatter(const float* P, const float* Tg, const uint32_t* hist,
                                                 unsigned long long* rec8, uint16_t* bidx) {
    int t = blockIdx.x;
    const float* src = task_src(t, P, Tg);
    const uint32_t* h = hist + (size_t)t * HTOT;
    __shared__ uint32_t sc[HTOT];
    for (int i = threadIdx.x; i < HTOT; i += 512) sc[i] = h[i];
    __syncthreads();
    int rep = (threadIdx.x >> 6) & 3;         // must match k_hist
    size_t base = (size_t)t << 15;
    for (int j4 = threadIdx.x; j4 < N_COLS / 4; j4 += 512) {
        float4 v = ((const float4*)src)[j4];
        float xs[4] = {v.x, v.y, v.z, v.w};
#pragma unroll
        for (int c = 0; c < 4; ++c) {
            uint32_t k = fkey(xs[c]);
            uint32_t pos = atomicAdd(&sc[((k >> SHIFT1) << 2) + rep], 1u);
            if (rec8) rec8[base + pos] = ((unsigned long long)k << 32) | (unsigned long long)(j4 * 4 + c);
            else      bidx[base + pos] = (uint16_t)(j4 * 4 + c);
        }
    }
}

// ---- K4: rank large buckets (m > 64) — ONE WAVE PER BUCKET, zero barriers ----
// Wave-synchronous: private LDS slice per wave; __threadfence_block (compiler fence +
// lgkmcnt wait, no s_barrier) orders LDS phases within the wave. 52 KB LDS -> 3
// blocks/CU = 12 independent waves/CU (was: 3 lockstep 4-wave groups, ~26 barriers/entry).
__global__ void __launch_bounds__(256) k_large(const float* P, const float* Tg,
                                               const unsigned long long* rec8, const uint16_t* bidx,
                                               uint16_t* sid,
                                               const uint32_t* cnts, const unsigned long long* list) {
    __shared__ uint32_t sk2[4][CAP_W];   // 32 KB
    __shared__ uint16_t si2[4][CAP_W];   // 16 KB
    __shared__ uint32_t sh[4][B2];       //  4 KB
    uint32_t w = threadIdx.x >> 6, lane = threadIdx.x & 63u;
    uint32_t gw = blockIdx.x * 4u + w;
    uint32_t nw = gridDim.x * 4u;
    uint32_t nlist = cnts[0];
    (void)P; (void)Tg; (void)bidx;
    for (uint32_t e = gw; e < nlist; e += nw) {
        unsigned long long ent = list[e];
        uint32_t t     = (uint32_t)(ent >> 32);
        uint32_t start = (uint32_t)(ent >> 16) & 0xFFFFu;
        uint32_t m     = (uint32_t)ent & 0xFFFFu;
        const unsigned long long* src = rec8 + ((size_t)t << 15) + start;
        size_t outb = ((size_t)t << 15) + start;
        if (m <= CAP_W) {
            // phase A: zero + sub-histogram on bits [20:13]
            for (uint32_t b = lane; b < B2; b += 64) sh[w][b] = 0;
            __threadfence_block();
            for (uint32_t i = lane; i < m; i += 64) {
                uint32_t k = (uint32_t)(src[i] >> 32);
                atomicAdd(&sh[w][(k >> SHIFT2) & MASK2], 1u);
            }
            __threadfence_block();
            // phase B: wave-scan of 256 bins (4 bins/lane, shfl inclusive scan)
            uint32_t b0 = sh[w][4 * lane], b1 = sh[w][4 * lane + 1];
            uint32_t b2 = sh[w][4 * lane + 2], b3 = sh[w][4 * lane + 3];
            uint32_t s4 = b0 + b1 + b2 + b3;
            uint32_t incl = s4;
#pragma unroll
            for (int off = 1; off < 64; off <<= 1) {
                uint32_t x = __shfl_up(incl, off, 64);
                if ((int)lane >= off) incl += x;
            }
            uint32_t excl = incl - s4;
            sh[w][4 * lane]     = excl;
            sh[w][4 * lane + 1] = excl + b0;
            sh[w][4 * lane + 2] = excl + b0 + b1;
            sh[w][4 * lane + 3] = excl + b0 + b1 + b2;
            __threadfence_block();
            // phase C: scatter bucket into LDS at sub-bin positions (cursor atomics)
            for (uint32_t i = lane; i < m; i += 64) {
                unsigned long long rr = src[i];
                uint32_t k = (uint32_t)(rr >> 32);
                uint32_t pos = atomicAdd(&sh[w][(k >> SHIFT2) & MASK2], 1u);
                sk2[w][pos] = k; si2[w][pos] = (uint16_t)(rr & 0xFFFFu);
            }
            __threadfence_block();
            // phase D: rank within same-19-bit group; sh now = inclusive ends
            for (uint32_t p2 = lane; p2 < m; p2 += 64) {
                uint32_t k = sk2[w][p2]; uint32_t id = si2[w][p2];
                uint32_t d2 = (k >> SHIFT2) & MASK2;
                uint32_t gs = d2 ? sh[w][d2 - 1] : 0u;
                uint32_t ge = sh[w][d2];
                uint32_t cnt = 0;
                for (uint32_t q = gs; q < ge; ++q) {
                    uint32_t kq = sk2[w][q];
                    cnt += (kq < k || (kq == k && (uint32_t)si2[w][q] < id)) ? 1u : 0u;
                }
                sid[outb + gs + cnt] = (uint16_t)id;
            }
            __threadfence_block();   // drain before next entry reuses the slice
        } else { // safety fallback (statistically unreachable): O(m^2) global, broadcast reads
            for (uint32_t i = lane; i < m; i += 64) {
                unsigned long long rr = src[i];
                uint32_t k = (uint32_t)(rr >> 32), id = (uint32_t)(rr & 0xFFFFu);
                uint32_t cnt = 0;
                for (uint32_t q = 0; q < m; ++q) {
                    unsigned long long rq = src[q];
                    uint32_t kq = (uint32_t)(rq >> 32), iq = (uint32_t)(rq & 0xFFFFu);
                    cnt += (kq < k || (kq == k && iq < id)) ? 1u : 0u;
                }
                sid[outb + cnt] = (uint16_t)id;
            }
        }
    }
}

// ---- K5: rank small buckets (1..64) — one wave per list entry ----
__global__ void __launch_bounds__(256) k_small(const float* P, const float* Tg,
                                               const unsigned long long* rec8, const uint16_t* bidx,
                                               uint16_t* sid,
                                               const uint32_t* cnts, const unsigned long long* slist) {
    uint32_t gw   = (blockIdx.x * 256u + threadIdx.x) >> 6;
    uint32_t lane = threadIdx.x & 63u;
    uint32_t nw   = (gridDim.x * 256u) >> 6;
    uint32_t nsl  = cnts[1];
    for (uint32_t e = gw; e < nsl; e += nw) {
        unsigned long long ent = slist[e];
        uint32_t t     = (uint32_t)(ent >> 32);
        uint32_t start = (uint32_t)(ent >> 16) & 0xFFFFu;
        uint32_t m     = (uint32_t)ent & 0xFFFFu;
        size_t base = (size_t)t << 15;
        uint32_t id = 0xFFFFFFFFu, k = 0u;
        if (lane < m) {
            if (rec8) { unsigned long long rr = rec8[base + start + lane]; k = (uint32_t)(rr >> 32); id = (uint32_t)(rr & 0xFFFFu); }
            else      { id = bidx[base + start + lane]; k = fkey(task_src((int)t, P, Tg)[id]); }
        }
        uint32_t cnt = 0;
        for (uint32_t q = 0; q < m; ++q) {
            uint32_t kq = __shfl(k, (int)q, 64);
            uint32_t iq = __shfl(id, (int)q, 64);
            cnt += (kq < k || (kq == k && iq < id)) ? 1u : 0u;
        }
        if (lane < m) sid[base + start + cnt] = (uint16_t)id;
    }
}

// ---- K6: per-row dot via LDS inverse permutation (no scattered global traffic) ----
__global__ void __launch_bounds__(1024) k_dot(const uint16_t* sid, double* rowloss) {
    extern __shared__ uint8_t smem[];
    uint16_t* inv = (uint16_t*)smem;    // 64 KB: inverse perm of targets row
    int r = blockIdx.x, tid = threadIdx.x;
    const uint4* t4 = (const uint4*)(sid + ((size_t)(r + N_ROWS) << 15));
    const uint4* p4 = (const uint4*)(sid + ((size_t)r << 15));
    for (int j8 = tid; j8 < N_COLS / 8; j8 += 1024) {
        uint4 v = t4[j8];
        uint32_t j = (uint32_t)j8 * 8u;
        inv[v.x & 0xFFFFu] = (uint16_t)(j + 0); inv[v.x >> 16] = (uint16_t)(j + 1);
        inv[v.y & 0xFFFFu] = (uint16_t)(j + 2); inv[v.y >> 16] = (uint16_t)(j + 3);
        inv[v.z & 0xFFFFu] = (uint16_t)(j + 4); inv[v.z >> 16] = (uint16_t)(j + 5);
        inv[v.w & 0xFFFFu] = (uint16_t)(j + 6); inv[v.w >> 16] = (uint16_t)(j + 7);
    }
    __syncthreads();
    unsigned long long s = 0;
    for (int j8 = tid; j8 < N_COLS / 8; j8 += 1024) {
        uint4 v = p4[j8];
        unsigned long long j = (unsigned long long)j8 * 8u;
        s += (j + 0) * (unsigned long long)inv[v.x & 0xFFFFu];
        s += (j + 1) * (unsigned long long)inv[v.x >> 16];
        s += (j + 2) * (unsigned long long)inv[v.y & 0xFFFFu];
        s += (j + 3) * (unsigned long long)inv[v.y >> 16];
        s += (j + 4) * (unsigned long long)inv[v.z & 0xFFFFu];
        s += (j + 5) * (unsigned long long)inv[v.z >> 16];
        s += (j + 6) * (unsigned long long)inv[v.w & 0xFFFFu];
        s += (j + 7) * (unsigned long long)inv[v.w >> 16];
    }
    for (int off = 32; off; off >>= 1) s += __shfl_down(s, off, 64);
    __shared__ unsigned long long sws[16];
    int w = tid >> 6, lane = tid & 63;
    if (lane == 0) sws[w] = s;
    __syncthreads();
    if (tid == 0) {
        unsigned long long tot = 0;
        for (int i = 0; i < 16; ++i) tot += sws[i];
        double S   = (double)tot;
        double num = S - 32768.0 * 16383.5 * 16383.5;        // S - n*mu^2 (exact)
        double den = 32768.0 * 1073741823.0 / 12.0;          // n(n^2-1)/12
        rowloss[r] = 1.0 - num / (den + 1e-8);
    }
}

// ---- K7: deterministic fixed-order final reduction ----
__global__ void __launch_bounds__(256) k_final(const double* rowloss, float* out) {
    __shared__ double s[256];
    s[threadIdx.x] = rowloss[threadIdx.x];
    __syncthreads();
    for (int off = 128; off; off >>= 1) {
        if ((int)threadIdx.x < off) s[threadIdx.x] += s[threadIdx.x + off];
        __syncthreads();
    }
    if (threadIdx.x == 0) out[0] = (float)(s[0] / 256.0);
}

extern "C" void kernel_launch(void* const* d_in, const int* in_sizes, int n_in,
                              void* d_out, int out_size, void* d_ws, size_t ws_size,
                              hipStream_t stream) {
    const float* P  = (const float*)d_in[0];
    const float* Tg = (const float*)d_in[1];
    float* out = (float*)d_out;
    char* ws = (char*)d_ws;
    const size_t MB = 1024 * 1024;

    uint32_t* hist = (uint32_t*)(ws);                                      // 16 MB (512 x 8192 u32)
    uint32_t* cnts = (uint32_t*)(ws + 16 * MB);                            // 16 B
    unsigned long long* list  = (unsigned long long*)(ws + 16 * MB + 4096); // ~2 MB max
    unsigned long long* slist = (unsigned long long*)(ws + 19 * MB);       // 8 MB max
    uint16_t* sid     = (uint16_t*)(ws + 27 * MB);                         // 32 MB
    double*   rowloss = (double*)(ws + 59 * MB);                           // 2 KB

    bool use_rec8 = (ws_size >= 189 * MB);
    unsigned long long* rec8 = nullptr;
    uint16_t* bidx = nullptr;
    if (use_rec8) rec8 = (unsigned long long*)(ws + 60 * MB);              // 128 MB
    else          bidx = (uint16_t*)(ws + 60 * MB);                        // 32 MB

    (void)hipFuncSetAttribute((const void*)k_dot,
                              hipFuncAttributeMaxDynamicSharedMemorySize, 65536);

    hipMemsetAsync(cnts, 0, 16, stream);

    k_hist   <<<N_TASKS, 512, 0, stream>>>(P, Tg, hist);
    k_scan   <<<N_TASKS, 256, 0, stream>>>(hist, cnts, list, slist);
    k_scatter<<<N_TASKS, 512, 0, stream>>>(P, Tg, hist, rec8, bidx);
    k_large  <<<4096, 256, 0, stream>>>(P, Tg, rec8, bidx, sid, cnts, list);
    k_small  <<<4096, 256, 0, stream>>>(P, Tg, rec8, bidx, sid, cnts, slist);
    k_dot    <<<N_ROWS, 1024, 65536, stream>>>(sid, rowloss);
    k_final  <<<1, 256, 0, stream>>>(rowloss, out);
}

// Round 8
// 399.270 us; speedup vs baseline: 1.1881x; 1.1881x over previous
//
#include <hip/hip_runtime.h>
#include <stdint.h>

#define N_COLS   32768
#define N_ROWS   256
#define N_TASKS  512          // 256 rows x {predictions, targets}
#define B1       2048         // level-1 bins (top 11 bits of key)
#define SHIFT1   21
#define B2V      512          // k_large sub-bins: key bits [20:12]
#define SMALL_THR 64u
#define CAP_W    2048         // per-wave LDS bucket capacity (expected max ~1800)
#define HREP     4            // per-wave histogram/cursor replicas (contention split)
#define HTOT     (B1 * HREP)  // 8192 u32 per task

// order-preserving float->uint32 key
__device__ __forceinline__ uint32_t fkey(float x) {
    uint32_t u = __float_as_uint(x);
    return u ^ ((uint32_t)((int32_t)u >> 31) | 0x80000000u);
}

__device__ __forceinline__ const float* task_src(int t, const float* P, const float* Tg) {
    return (t < N_ROWS ? P : Tg) + (size_t)(t & (N_ROWS - 1)) * N_COLS;
}

// ---- K1: per-task histogram, 4 replicas per bin (measured-good) ----
// element->replica mapping (512 threads, j4 stride 512, rep=(tid>>6)&3) MUST match k_scatter.
__global__ void __launch_bounds__(512) k_hist(const float* P, const float* Tg, uint32_t* hist) {
    int t = blockIdx.x;
    const float* src = task_src(t, P, Tg);
    __shared__ uint32_t h[HTOT];
    for (int i = threadIdx.x; i < HTOT; i += 512) h[i] = 0;
    __syncthreads();
    int rep = (threadIdx.x >> 6) & 3;
    for (int j4 = threadIdx.x; j4 < N_COLS / 4; j4 += 512) {
        float4 v = ((const float4*)src)[j4];
        atomicAdd(&h[((fkey(v.x) >> SHIFT1) << 2) + rep], 1u);
        atomicAdd(&h[((fkey(v.y) >> SHIFT1) << 2) + rep], 1u);
        atomicAdd(&h[((fkey(v.z) >> SHIFT1) << 2) + rep], 1u);
        atomicAdd(&h[((fkey(v.w) >> SHIFT1) << 2) + rep], 1u);
    }
    __syncthreads();
    uint32_t* o = hist + (size_t)t * HTOT;
    for (int i = threadIdx.x; i < HTOT; i += 512) o[i] = h[i];
}

// ---- K2: per-task exclusive prefix -> per-replica cursors + work lists ----
__global__ void __launch_bounds__(256) k_scan(uint32_t* hist, uint32_t* cnts,
                                              unsigned long long* list, unsigned long long* slist) {
    int t = blockIdx.x;
    uint4* h4 = (uint4*)(hist + (size_t)t * HTOT);
    __shared__ uint32_t stmp[256];
    uint32_t run = 0;
    for (int c = 0; c < B1 / 256; ++c) {
        int bin = c * 256 + threadIdx.x;
        uint4 hv = h4[bin];
        uint32_t v = hv.x + hv.y + hv.z + hv.w;
        stmp[threadIdx.x] = v;
        __syncthreads();
        for (int off = 1; off < 256; off <<= 1) {
            uint32_t x = (threadIdx.x >= (unsigned)off) ? stmp[threadIdx.x - off] : 0u;
            __syncthreads();
            stmp[threadIdx.x] += x;
            __syncthreads();
        }
        uint32_t incl = stmp[threadIdx.x];
        uint32_t tot  = stmp[255];
        uint32_t start = run + incl - v;     // task-local exclusive prefix (bucket start)
        if (v > SMALL_THR) {
            uint32_t p = atomicAdd(&cnts[0], 1u);
            list[p] = ((unsigned long long)t << 32) | ((unsigned long long)start << 16) | v;
        } else if (v) {
            uint32_t p = atomicAdd(&cnts[1], 1u);
            slist[p] = ((unsigned long long)t << 32) | ((unsigned long long)start << 16) | v;
        }
        uint4 w;                              // per-replica cursor starts
        w.x = start;
        w.y = w.x + hv.x;
        w.z = w.y + hv.y;
        w.w = w.z + hv.z;
        h4[bin] = w;
        run += tot;
        __syncthreads();
    }
}

// ---- K3: counting-sort scatter, LDS cursors, ONE packed 8B store per element ----
__global__ void __launch_bounds__(512) k_scatter(const float* P, const float* Tg, const uint32_t* hist,
                                                 unsigned long long* rec8, uint16_t* bidx) {
    int t = blockIdx.x;
    const float* src = task_src(t, P, Tg);
    const uint32_t* h = hist + (size_t)t * HTOT;
    __shared__ uint32_t sc[HTOT];
    for (int i = threadIdx.x; i < HTOT; i += 512) sc[i] = h[i];
    __syncthreads();
    int rep = (threadIdx.x >> 6) & 3;         // must match k_hist
    size_t base = (size_t)t << 15;
    for (int j4 = threadIdx.x; j4 < N_COLS / 4; j4 += 512) {
        float4 v = ((const float4*)src)[j4];
        float xs[4] = {v.x, v.y, v.z, v.w};
#pragma unroll
        for (int c = 0; c < 4; ++c) {
            uint32_t k = fkey(xs[c]);
            uint32_t pos = atomicAdd(&sc[((k >> SHIFT1) << 2) + rep], 1u);
            if (rec8) rec8[base + pos] = ((unsigned long long)k << 32) | (unsigned long long)(j4 * 4 + c);
            else      bidx[base + pos] = (uint16_t)(j4 * 4 + c);
        }
    }
}

// ---- K4: rank large buckets (m > 64) — wave-per-bucket, packed-u32, group-centric ----
// Sub-bin on key bits [20:12] (512 bins). Within a sub-bin group all keys share bits
// [31:12], so comparator (k<,tie:id<) == u32 compare of ((k&0xFFF)<<15)|id.
// Per-wave LDS slice 10 KB -> block 40960 B -> 4 blocks/CU = 16 waves/CU.
__global__ void __launch_bounds__(256) k_large(const float* P, const float* Tg,
                                               const unsigned long long* rec8, const uint16_t* bidx,
                                               uint16_t* sid,
                                               const uint32_t* cnts, const unsigned long long* list) {
    __shared__ uint32_t sk2[4][CAP_W];   // 32 KB: packed cmp values, grouped by sub-bin
    __shared__ uint32_t sh[4][B2V];      //  8 KB: sub-bin hist/cursors/ends
    uint32_t w = threadIdx.x >> 6, lane = threadIdx.x & 63u;
    uint32_t gw = blockIdx.x * 4u + w;
    uint32_t nw = gridDim.x * 4u;
    uint32_t nlist = cnts[0];
    (void)P; (void)Tg; (void)bidx;
    for (uint32_t e = gw; e < nlist; e += nw) {
        unsigned long long ent = list[e];
        uint32_t t     = (uint32_t)(ent >> 32);
        uint32_t start = (uint32_t)(ent >> 16) & 0xFFFFu;
        uint32_t m     = (uint32_t)ent & 0xFFFFu;
        const uint2* src2 = (const uint2*)(rec8 + ((size_t)t << 15) + start);  // .x=id, .y=key
        size_t outb = ((size_t)t << 15) + start;
        if (m <= CAP_W) {
            // phase A: zero + sub-histogram on bits [20:12]; paired loads for ILP
            for (uint32_t b = lane; b < B2V; b += 64) sh[w][b] = 0;
            __threadfence_block();
            for (uint32_t i = lane; i < m; i += 128) {
                uint2 ra = src2[i];
                uint32_t i2 = i + 64; bool hb = i2 < m;
                uint2 rb; if (hb) rb = src2[i2];
                atomicAdd(&sh[w][(ra.y >> 12) & (B2V - 1u)], 1u);
                if (hb) atomicAdd(&sh[w][(rb.y >> 12) & (B2V - 1u)], 1u);
            }
            __threadfence_block();
            // phase B: wave-scan of 512 bins (8 bins/lane, shfl inclusive scan)
            uint32_t bb[8]; uint32_t s8 = 0;
#pragma unroll
            for (int j = 0; j < 8; ++j) { bb[j] = sh[w][8 * lane + j]; s8 += bb[j]; }
            uint32_t incl = s8;
#pragma unroll
            for (int off = 1; off < 64; off <<= 1) {
                uint32_t x = __shfl_up(incl, off, 64);
                if ((int)lane >= off) incl += x;
            }
            uint32_t excl = incl - s8;
#pragma unroll
            for (int j = 0; j < 8; ++j) { sh[w][8 * lane + j] = excl; excl += bb[j]; }
            __threadfence_block();
            // phase C: scatter packed cmp into LDS at sub-bin cursors; paired loads
            for (uint32_t i = lane; i < m; i += 128) {
                uint2 ra = src2[i];
                uint32_t i2 = i + 64; bool hb = i2 < m;
                uint2 rb; if (hb) rb = src2[i2];
                uint32_t pa = atomicAdd(&sh[w][(ra.y >> 12) & (B2V - 1u)], 1u);
                sk2[w][pa] = ((ra.y & 0xFFFu) << 15) | (ra.x & 0x7FFFu);
                if (hb) {
                    uint32_t pb = atomicAdd(&sh[w][(rb.y >> 12) & (B2V - 1u)], 1u);
                    sk2[w][pb] = ((rb.y & 0xFFFu) << 15) | (rb.x & 0x7FFFu);
                }
            }
            __threadfence_block();
            // phase D: group-centric rank; sh now = inclusive ends; 4x-unrolled compares
            for (uint32_t d2 = lane; d2 < B2V; d2 += 64) {
                uint32_t gs = d2 ? sh[w][d2 - 1] : 0u;
                uint32_t ge = sh[w][d2];
                for (uint32_t p = gs; p < ge; ++p) {
                    uint32_t pi = sk2[w][p];
                    uint32_t cnt = 0, q = gs;
                    for (; q + 4 <= ge; q += 4) {
                        uint32_t a = sk2[w][q], b = sk2[w][q + 1];
                        uint32_t c = sk2[w][q + 2], d = sk2[w][q + 3];
                        cnt += (a < pi) + (b < pi) + (c < pi) + (d < pi);
                    }
                    for (; q < ge; ++q) cnt += (sk2[w][q] < pi) ? 1u : 0u;
                    sid[outb + gs + cnt] = (uint16_t)(pi & 0x7FFFu);
                }
            }
            __threadfence_block();   // drain before next entry reuses the slice
        } else { // safety fallback (statistically unreachable): O(m^2) global, broadcast reads
            const unsigned long long* src = rec8 + ((size_t)t << 15) + start;
            for (uint32_t i = lane; i < m; i += 64) {
                unsigned long long rr = src[i];
                uint32_t k = (uint32_t)(rr >> 32), id = (uint32_t)(rr & 0xFFFFu);
                uint32_t cnt = 0;
                for (uint32_t q = 0; q < m; ++q) {
                    unsigned long long rq = src[q];
                    uint32_t kq = (uint32_t)(rq >> 32), iq = (uint32_t)(rq & 0xFFFFu);
                    cnt += (kq < k || (kq == k && iq < id)) ? 1u : 0u;
                }
                sid[outb + cnt] = (uint16_t)id;
            }
        }
    }
}

// ---- K5: rank small buckets (1..64) — one wave per list entry ----
__global__ void __launch_bounds__(256) k_small(const float* P, const float* Tg,
                                               const unsigned long long* rec8, const uint16_t* bidx,
                                               uint16_t* sid,
                                               const uint32_t* cnts, const unsigned long long* slist) {
    uint32_t gw   = (blockIdx.x * 256u + threadIdx.x) >> 6;
    uint32_t lane = threadIdx.x & 63u;
    uint32_t nw   = (gridDim.x * 256u) >> 6;
    uint32_t nsl  = cnts[1];
    for (uint32_t e = gw; e < nsl; e += nw) {
        unsigned long long ent = slist[e];
        uint32_t t     = (uint32_t)(ent >> 32);
        uint32_t start = (uint32_t)(ent >> 16) & 0xFFFFu;
        uint32_t m     = (uint32_t)ent & 0xFFFFu;
        size_t base = (size_t)t << 15;
        uint32_t id = 0xFFFFFFFFu, k = 0u;
        if (lane < m) {
            if (rec8) { unsigned long long rr = rec8[base + start + lane]; k = (uint32_t)(rr >> 32); id = (uint32_t)(rr & 0xFFFFu); }
            else      { id = bidx[base + start + lane]; k = fkey(task_src((int)t, P, Tg)[id]); }
        }
        uint32_t cnt = 0;
        for (uint32_t q = 0; q < m; ++q) {
            uint32_t kq = __shfl(k, (int)q, 64);
            uint32_t iq = __shfl(id, (int)q, 64);
            cnt += (kq < k || (kq == k && iq < id)) ? 1u : 0u;
        }
        if (lane < m) sid[base + start + cnt] = (uint16_t)id;
    }
}

// ---- K6: per-row dot via LDS inverse permutation (no scattered global traffic) ----
__global__ void __launch_bounds__(1024) k_dot(const uint16_t* sid, double* rowloss) {
    extern __shared__ uint8_t smem[];
    uint16_t* inv = (uint16_t*)smem;    // 64 KB: inverse perm of targets row
    int r = blockIdx.x, tid = threadIdx.x;
    const uint4* t4 = (const uint4*)(sid + ((size_t)(r + N_ROWS) << 15));
    const uint4* p4 = (const uint4*)(sid + ((size_t)r << 15));
    for (int j8 = tid; j8 < N_COLS / 8; j8 += 1024) {
        uint4 v = t4[j8];
        uint32_t j = (uint32_t)j8 * 8u;
        inv[v.x & 0xFFFFu] = (uint16_t)(j + 0); inv[v.x >> 16] = (uint16_t)(j + 1);
        inv[v.y & 0xFFFFu] = (uint16_t)(j + 2); inv[v.y >> 16] = (uint16_t)(j + 3);
        inv[v.z & 0xFFFFu] = (uint16_t)(j + 4); inv[v.z >> 16] = (uint16_t)(j + 5);
        inv[v.w & 0xFFFFu] = (uint16_t)(j + 6); inv[v.w >> 16] = (uint16_t)(j + 7);
    }
    __syncthreads();
    unsigned long long s = 0;
    for (int j8 = tid; j8 < N_COLS / 8; j8 += 1024) {
        uint4 v = p4[j8];
        unsigned long long j = (unsigned long long)j8 * 8u;
        s += (j + 0) * (unsigned long long)inv[v.x & 0xFFFFu];
        s += (j + 1) * (unsigned long long)inv[v.x >> 16];
        s += (j + 2) * (unsigned long long)inv[v.y & 0xFFFFu];
        s += (j + 3) * (unsigned long long)inv[v.y >> 16];
        s += (j + 4) * (unsigned long long)inv[v.z & 0xFFFFu];
        s += (j + 5) * (unsigned long long)inv[v.z >> 16];
        s += (j + 6) * (unsigned long long)inv[v.w & 0xFFFFu];
        s += (j + 7) * (unsigned long long)inv[v.w >> 16];
    }
    for (int off = 32; off; off >>= 1) s += __shfl_down(s, off, 64);
    __shared__ unsigned long long sws[16];
    int w = tid >> 6, lane = tid & 63;
    if (lane == 0) sws[w] = s;
    __syncthreads();
    if (tid == 0) {
        unsigned long long tot = 0;
        for (int i = 0; i < 16; ++i) tot += sws[i];
        double S   = (double)tot;
        double num = S - 32768.0 * 16383.5 * 16383.5;        // S - n*mu^2 (exact)
        double den = 32768.0 * 1073741823.0 / 12.0;          // n(n^2-1)/12
        rowloss[r] = 1.0 - num / (den + 1e-8);
    }
}

// ---- K7: deterministic fixed-order final reduction ----
__global__ void __launch_bounds__(256) k_final(const double* rowloss, float* out) {
    __shared__ double s[256];
    s[threadIdx.x] = rowloss[threadIdx.x];
    __syncthreads();
    for (int off = 128; off; off >>= 1) {
        if ((int)threadIdx.x < off) s[threadIdx.x] += s[threadIdx.x + off];
        __syncthreads();
    }
    if (threadIdx.x == 0) out[0] = (float)(s[0] / 256.0);
}

extern "C" void kernel_launch(void* const* d_in, const int* in_sizes, int n_in,
                              void* d_out, int out_size, void* d_ws, size_t ws_size,
                              hipStream_t stream) {
    const float* P  = (const float*)d_in[0];
    const float* Tg = (const float*)d_in[1];
    float* out = (float*)d_out;
    char* ws = (char*)d_ws;
    const size_t MB = 1024 * 1024;

    uint32_t* hist = (uint32_t*)(ws);                                      // 16 MB (512 x 8192 u32)
    uint32_t* cnts = (uint32_t*)(ws + 16 * MB);                            // 16 B
    unsigned long long* list  = (unsigned long long*)(ws + 16 * MB + 4096); // ~2 MB max
    unsigned long long* slist = (unsigned long long*)(ws + 19 * MB);       // 8 MB max
    uint16_t* sid     = (uint16_t*)(ws + 27 * MB);                         // 32 MB
    double*   rowloss = (double*)(ws + 59 * MB);                           // 2 KB

    bool use_rec8 = (ws_size >= 189 * MB);
    unsigned long long* rec8 = nullptr;
    uint16_t* bidx = nullptr;
    if (use_rec8) rec8 = (unsigned long long*)(ws + 60 * MB);              // 128 MB
    else          bidx = (uint16_t*)(ws + 60 * MB);                        // 32 MB

    (void)hipFuncSetAttribute((const void*)k_dot,
                              hipFuncAttributeMaxDynamicSharedMemorySize, 65536);

    hipMemsetAsync(cnts, 0, 16, stream);

    k_hist   <<<N_TASKS, 512, 0, stream>>>(P, Tg, hist);
    k_scan   <<<N_TASKS, 256, 0, stream>>>(hist, cnts, list, slist);
    k_scatter<<<N_TASKS, 512, 0, stream>>>(P, Tg, hist, rec8, bidx);
    k_large  <<<4096, 256, 0, stream>>>(P, Tg, rec8, bidx, sid, cnts, list);
    k_small  <<<4096, 256, 0, stream>>>(P, Tg, rec8, bidx, sid, cnts, slist);
    k_dot    <<<N_ROWS, 1024, 65536, stream>>>(sid, rowloss);
    k_final  <<<1, 256, 0, stream>>>(rowloss, out);
}